// Round 2
// baseline (2194.913 us; speedup 1.0000x reference)
//
#include <hip/hip_runtime.h>

// Sizes fixed by the reference: C=64, D=64 grid, ds grid 32^3.
#define GD 64
#define GDS 32

// ---------------------------------------------------------------------------
// init: idx_grid = -1 (64^3), ds_mask = 0 (32^3)
__global__ __launch_bounds__(256) void init_kernel(int* __restrict__ idx_grid,
                                                   unsigned char* __restrict__ ds_mask) {
    int i = blockIdx.x * 256 + threadIdx.x;
    if (i < GD * GD * GD) idx_grid[i] = -1;
    if (i < GDS * GDS * GDS) ds_mask[i] = 0;
}

// scatter: point index into idx_grid, 1 into ds_mask
__global__ __launch_bounds__(256) void scatter_kernel(const int* __restrict__ coords, int N,
                                                      const int* __restrict__ coords_ds, int M,
                                                      int* __restrict__ idx_grid,
                                                      unsigned char* __restrict__ ds_mask) {
    int i = blockIdx.x * 256 + threadIdx.x;
    if (i < N) {
        int a = coords[i * 3], b = coords[i * 3 + 1], c = coords[i * 3 + 2];
        idx_grid[(a * GD + b) * GD + c] = i;
    }
    if (i < M) {
        int a = coords_ds[i * 3], b = coords_ds[i * 3 + 1], c = coords_ds[i * 3 + 2];
        ds_mask[(a * GDS + b) * GDS + c] = 1;
    }
}

// ---------------------------------------------------------------------------
// conv1: 3x3x3, 128 -> 64, output only at the N active sites (gather form).
// Block = 32 points x 256 threads. Per tap: stage W (128x64, 32KB) + gathered
// rows (32x128, 16KB) in LDS. Thread (c, pg): 8 point-accumulators for one
// output channel. xs reads broadcast within a wave (whole wave shares pg);
// ws reads are stride-1 across lanes (conflict-free).
__global__ __launch_bounds__(256) void conv1_kernel(const int* __restrict__ coords, int N,
                                                    const float* __restrict__ fc1,
                                                    const float* __restrict__ fref,
                                                    const float* __restrict__ w,  // 27*128*64
                                                    const float* __restrict__ b,  // 64
                                                    const int* __restrict__ idx_grid,
                                                    float* __restrict__ out /* N x 64 */) {
    __shared__ float xs[32 * 128];
    __shared__ float ws[128 * 64];
    __shared__ int nbr[32 * 27];
    __shared__ int pc[32 * 3];

    int tid = threadIdx.x;
    int p0 = blockIdx.x * 32;

    if (tid < 96) {
        int p = tid / 3, d = tid % 3;
        int gp = p0 + p;
        pc[tid] = (gp < N) ? coords[gp * 3 + d] : -1000;
    }
    __syncthreads();
    for (int t = tid; t < 32 * 27; t += 256) {
        int p = t / 27, tap = t % 27;
        int i = pc[p * 3 + 0] + tap / 9 - 1;
        int j = pc[p * 3 + 1] + (tap / 3) % 3 - 1;
        int k = pc[p * 3 + 2] + tap % 3 - 1;
        int nb = -1;
        if ((unsigned)i < (unsigned)GD && (unsigned)j < (unsigned)GD && (unsigned)k < (unsigned)GD)
            nb = idx_grid[(i * GD + j) * GD + k];
        nbr[t] = nb;
    }

    int c = tid & 63, pg = tid >> 6;
    float acc[8];
#pragma unroll
    for (int q = 0; q < 8; ++q) acc[q] = 0.f;

    for (int tap = 0; tap < 27; ++tap) {
        __syncthreads();
        {  // weights: 8192 floats = 2048 float4
            const float4* src = (const float4*)(w + tap * 8192);
            float4* dst = (float4*)ws;
            for (int t = tid; t < 2048; t += 256) dst[t] = src[t];
        }
        {  // gathered rows: 32 points x 128 ch; thread -> (point, 16-float segment)
            int p = tid >> 3, seg = tid & 7;
            int nb = nbr[p * 27 + tap];
            float4* dst = (float4*)&xs[p * 128 + seg * 16];
            if (nb >= 0) {
                const float* srcrow = (seg < 4) ? (fc1 + (size_t)nb * 64 + seg * 16)
                                                : (fref + (size_t)nb * 64 + seg * 16 - 64);
                const float4* s4 = (const float4*)srcrow;
                dst[0] = s4[0]; dst[1] = s4[1]; dst[2] = s4[2]; dst[3] = s4[3];
            } else {
                float4 z = make_float4(0.f, 0.f, 0.f, 0.f);
                dst[0] = z; dst[1] = z; dst[2] = z; dst[3] = z;
            }
        }
        __syncthreads();
        for (int ic = 0; ic < 128; ic += 4) {
            float w0 = ws[(ic + 0) * 64 + c], w1 = ws[(ic + 1) * 64 + c];
            float w2 = ws[(ic + 2) * 64 + c], w3 = ws[(ic + 3) * 64 + c];
#pragma unroll
            for (int q = 0; q < 8; ++q) {
                const float4 xv = *(const float4*)&xs[(pg * 8 + q) * 128 + ic];
                acc[q] += xv.x * w0 + xv.y * w1 + xv.z * w2 + xv.w * w3;
            }
        }
    }
    float bias = b[c];
#pragma unroll
    for (int q = 0; q < 8; ++q) {
        int p = p0 + pg * 8 + q;
        if (p < N) {
            float v = acc[q] + bias;
            out[(size_t)p * 64 + c] = v > 0.f ? v : 0.f;
        }
    }
}

// ---------------------------------------------------------------------------
// down: 2x2x2 stride-2 VALID, 64 -> 64, input = sparse feats1 via idx_grid,
// output dense 32^3 x 64 (0 at masked-out sites). Block = 8 ds-sites.
__global__ __launch_bounds__(256) void down_kernel(const float* __restrict__ feats1,
                                                   const int* __restrict__ idx_grid,
                                                   const float* __restrict__ w,  // 8*64*64
                                                   const float* __restrict__ b,
                                                   const unsigned char* __restrict__ ds_mask,
                                                   float* __restrict__ out /* 32^3 x 64 */) {
    __shared__ float xs[8 * 8 * 64];
    __shared__ float wt[64 * 64];
    int tid = threadIdx.x;
    int s0 = blockIdx.x * 8;

    for (int idx = tid; idx < 8 * 8 * 64; idx += 256) {
        int s_l = idx >> 9, t = (idx >> 6) & 7, ic = idx & 63;
        int s = s0 + s_l;
        int i = s >> 10, j = (s >> 5) & 31, k = s & 31;
        int ci = 2 * i + (t >> 2), cj = 2 * j + ((t >> 1) & 1), ck = 2 * k + (t & 1);
        int r = idx_grid[(ci * GD + cj) * GD + ck];
        xs[idx] = (r >= 0) ? feats1[(size_t)r * 64 + ic] : 0.f;
    }

    int oc = tid & 63, sg = tid >> 6;
    float acc[2] = {0.f, 0.f};
    for (int t = 0; t < 8; ++t) {
        __syncthreads();
        for (int idx = tid; idx < 4096; idx += 256) wt[idx] = w[t * 4096 + idx];
        __syncthreads();
        for (int ic = 0; ic < 64; ic += 4) {
            float w0 = wt[(ic + 0) * 64 + oc], w1 = wt[(ic + 1) * 64 + oc];
            float w2 = wt[(ic + 2) * 64 + oc], w3 = wt[(ic + 3) * 64 + oc];
#pragma unroll
            for (int q = 0; q < 2; ++q) {
                const float4 xv = *(const float4*)&xs[((sg * 2 + q) * 8 + t) * 64 + ic];
                acc[q] += xv.x * w0 + xv.y * w1 + xv.z * w2 + xv.w * w3;
            }
        }
    }
    float bias = b[oc];
#pragma unroll
    for (int q = 0; q < 2; ++q) {
        int s = s0 + sg * 2 + q;
        float v = 0.f;
        if (ds_mask[s]) {
            v = acc[q] + bias;
            v = v > 0.f ? v : 0.f;
        }
        out[(size_t)s * 64 + oc] = v;
    }
}

// ---------------------------------------------------------------------------
// Generic masked conv on the dense 32^3 grid. KS in {1,3}. Fused bias, relu,
// mask (write 0 at masked-out sites), optional residual add (res stride 64),
// output channel offset (implements the concat) and output stride.
template <int CIN, int COUT, int KS, bool RELU, bool HASRES>
__global__ __launch_bounds__(256) void sconv_kernel(const float* __restrict__ in,  // 32^3 x CIN
                                                    const float* __restrict__ w,   // KS^3*CIN*COUT
                                                    const float* __restrict__ b,   // COUT
                                                    const unsigned char* __restrict__ ds_mask,
                                                    const float* __restrict__ res,  // 32^3 x 64
                                                    float* __restrict__ out, int ostride, int ooff) {
    constexpr int T = KS * KS * KS;
    constexpr int NS = COUT / 16;  // sites per thread (block covers 16 sites)
    constexpr int XROW = CIN + 4;  // pad to spread banks, keeps 16B alignment
    __shared__ float xs[16 * XROW];
    __shared__ float wt[CIN * COUT];

    int tid = threadIdx.x;
    int s0 = blockIdx.x * 16;
    int i0 = s0 >> 10, j0 = (s0 >> 5) & 31, k0 = s0 & 31;
    int oc = tid % COUT, sg = tid / COUT;

    float acc[NS];
#pragma unroll
    for (int q = 0; q < NS; ++q) acc[q] = 0.f;

    for (int tap = 0; tap < T; ++tap) {
        int dz = (KS == 3) ? tap / 9 - 1 : 0;
        int dy = (KS == 3) ? (tap / 3) % 3 - 1 : 0;
        int dx = (KS == 3) ? tap % 3 - 1 : 0;
        __syncthreads();
        for (int idx = tid; idx < CIN * COUT; idx += 256) wt[idx] = w[tap * CIN * COUT + idx];
        int ni = i0 + dz, nj = j0 + dy;
        bool rowok = ((unsigned)ni < (unsigned)GDS) && ((unsigned)nj < (unsigned)GDS);
        for (int idx = tid; idx < 16 * CIN; idx += 256) {
            int s_l = idx / CIN, ic = idx % CIN;
            int nk = k0 + s_l + dx;
            float v = 0.f;
            if (rowok && (unsigned)nk < (unsigned)GDS)
                v = in[(size_t)((ni * GDS + nj) * GDS + nk) * CIN + ic];
            xs[s_l * XROW + ic] = v;
        }
        __syncthreads();
        for (int ic = 0; ic < CIN; ic += 4) {
            float w0 = wt[(ic + 0) * COUT + oc], w1 = wt[(ic + 1) * COUT + oc];
            float w2 = wt[(ic + 2) * COUT + oc], w3 = wt[(ic + 3) * COUT + oc];
#pragma unroll
            for (int q = 0; q < NS; ++q) {
                const float4 xv = *(const float4*)&xs[(sg * NS + q) * XROW + ic];
                acc[q] += xv.x * w0 + xv.y * w1 + xv.z * w2 + xv.w * w3;
            }
        }
    }
    float bias = b[oc];
#pragma unroll
    for (int q = 0; q < NS; ++q) {
        int s = s0 + sg * NS + q;
        float v = 0.f;
        if (ds_mask[s]) {
            v = acc[q] + bias;
            if (RELU) v = v > 0.f ? v : 0.f;
        }
        if (HASRES) v += res[(size_t)s * 64 + ooff + oc];
        out[(size_t)s * ostride + ooff + oc] = v;
    }
}

// final gather: out[m][oc] = x[ds_site(m)][oc]
__global__ __launch_bounds__(256) void gather_kernel(const float* __restrict__ x,
                                                     const int* __restrict__ coords_ds, int M,
                                                     float* __restrict__ out) {
    int i = blockIdx.x * 256 + threadIdx.x;
    if (i < M * 64) {
        int m = i >> 6, oc = i & 63;
        int a = coords_ds[m * 3], b = coords_ds[m * 3 + 1], c = coords_ds[m * 3 + 2];
        out[i] = x[((size_t)((a * GDS + b) * GDS + c) << 6) + oc];
    }
}

// ---------------------------------------------------------------------------
extern "C" void kernel_launch(void* const* d_in, const int* in_sizes, int n_in,
                              void* d_out, int out_size, void* d_ws, size_t ws_size,
                              hipStream_t stream) {
    const int* coords = (const int*)d_in[0];
    const int* coords_ds = (const int*)d_in[1];
    const float* fc1 = (const float*)d_in[2];
    const float* fref = (const float*)d_in[3];
    const float* w_fuse = (const float*)d_in[4];
    const float* b_fuse = (const float*)d_in[5];
    const float* w_down = (const float*)d_in[6];
    const float* b_down = (const float*)d_in[7];
    const float* w_conv2 = (const float*)d_in[8];
    const float* b_conv2 = (const float*)d_in[9];
    const float* w_p00 = (const float*)d_in[10];
    const float* b_p00 = (const float*)d_in[11];
    const float* w_p01 = (const float*)d_in[12];
    const float* b_p01 = (const float*)d_in[13];
    const float* w_p10 = (const float*)d_in[14];
    const float* b_p10 = (const float*)d_in[15];
    const float* w_p11 = (const float*)d_in[16];
    const float* b_p11 = (const float*)d_in[17];
    const float* w_p12 = (const float*)d_in[18];
    const float* b_p12 = (const float*)d_in[19];

    const int N = in_sizes[0] / 3;
    const int M = in_sizes[1] / 3;
    const int L = in_sizes[10] / (27 * 64 * 16);
    const int NSITES = GDS * GDS * GDS;  // 32768

    // workspace carve-up (~48 MB)
    size_t off = 0;
    auto alloc = [&](size_t bytes) {
        void* p = (char*)d_ws + off;
        off += (bytes + 255) & ~(size_t)255;
        return p;
    };
    int* idx_grid = (int*)alloc((size_t)GD * GD * GD * 4);
    unsigned char* ds_mask = (unsigned char*)alloc(NSITES);
    float* feats1 = (float*)alloc((size_t)N * 64 * 4);
    float* xA = (float*)alloc((size_t)NSITES * 64 * 4);
    float* xB = (float*)alloc((size_t)NSITES * 64 * 4);
    float* t16a = (float*)alloc((size_t)NSITES * 16 * 4);
    float* t16b = (float*)alloc((size_t)NSITES * 16 * 4);
    (void)ws_size;

    float* out = (float*)d_out;
    (void)out_size; (void)n_in;

    init_kernel<<<(GD * GD * GD) / 256, 256, 0, stream>>>(idx_grid, ds_mask);
    {
        int mx = N > M ? N : M;
        scatter_kernel<<<(mx + 255) / 256, 256, 0, stream>>>(coords, N, coords_ds, M, idx_grid,
                                                             ds_mask);
    }
    conv1_kernel<<<(N + 31) / 32, 256, 0, stream>>>(coords, N, fc1, fref, w_fuse, b_fuse, idx_grid,
                                                    feats1);
    down_kernel<<<NSITES / 8, 256, 0, stream>>>(feats1, idx_grid, w_down, b_down, ds_mask, xB);
    sconv_kernel<64, 64, 3, false, false>
        <<<NSITES / 16, 256, 0, stream>>>(xB, w_conv2, b_conv2, ds_mask, nullptr, xA, 64, 0);

    float* x = xA;
    float* y = xB;
    for (int i = 0; i < L; ++i) {
        const float* wp00 = w_p00 + (size_t)i * 27 * 64 * 16;
        const float* bp00 = b_p00 + (size_t)i * 16;
        const float* wp01 = w_p01 + (size_t)i * 27 * 16 * 32;
        const float* bp01 = b_p01 + (size_t)i * 32;
        const float* wp10 = w_p10 + (size_t)i * 64 * 16;
        const float* bp10 = b_p10 + (size_t)i * 16;
        const float* wp11 = w_p11 + (size_t)i * 27 * 16 * 16;
        const float* bp11 = b_p11 + (size_t)i * 16;
        const float* wp12 = w_p12 + (size_t)i * 16 * 32;
        const float* bp12 = b_p12 + (size_t)i * 32;

        // p0 = relu(conv3(x, w00)); p0 = conv3(p0, w01) -> y[:,0:32] += x[:,0:32]
        sconv_kernel<64, 16, 3, true, false>
            <<<NSITES / 16, 256, 0, stream>>>(x, wp00, bp00, ds_mask, nullptr, t16a, 16, 0);
        sconv_kernel<16, 32, 3, false, true>
            <<<NSITES / 16, 256, 0, stream>>>(t16a, wp01, bp01, ds_mask, x, y, 64, 0);
        // p1 = relu(conv1(x, w10)); p1 = relu(conv3(p1, w11)); p1 = conv1(p1, w12)
        //   -> y[:,32:64] += x[:,32:64]
        sconv_kernel<64, 16, 1, true, false>
            <<<NSITES / 16, 256, 0, stream>>>(x, wp10, bp10, ds_mask, nullptr, t16b, 16, 0);
        sconv_kernel<16, 16, 3, true, false>
            <<<NSITES / 16, 256, 0, stream>>>(t16b, wp11, bp11, ds_mask, nullptr, t16a, 16, 0);
        sconv_kernel<16, 32, 1, false, true>
            <<<NSITES / 16, 256, 0, stream>>>(t16a, wp12, bp12, ds_mask, x, y, 64, 32);
        // swap ping-pong
        float* tmp = x; x = y; y = tmp;
    }

    gather_kernel<<<(M * 64 + 255) / 256, 256, 0, stream>>>(x, coords_ds, M, out);
}

// Round 3
// 1110.387 us; speedup vs baseline: 1.9767x; 1.9767x over previous
//
#include <hip/hip_runtime.h>

// Sizes fixed by the reference: C=64, D=64 grid, ds grid 32^3.
#define GD 64
#define GDS 32

typedef __attribute__((ext_vector_type(8))) short bf16x8;
typedef __attribute__((ext_vector_type(4))) float f32x4;

__device__ __forceinline__ ushort f2bf(float x) {
    union { float f; unsigned u; } v; v.f = x;
    unsigned r = v.u + 0x7fff + ((v.u >> 16) & 1);  // round-to-nearest-even
    return (ushort)(r >> 16);
}

// ---------------------------------------------------------------------------
// init: idx_grid = -1 (64^3), ds_mask = 0 (32^3)
__global__ __launch_bounds__(256) void init_kernel(int* __restrict__ idx_grid,
                                                   unsigned char* __restrict__ ds_mask) {
    int i = blockIdx.x * 256 + threadIdx.x;
    if (i < GD * GD * GD) idx_grid[i] = -1;
    if (i < GDS * GDS * GDS) ds_mask[i] = 0;
}

// scatter: point index into idx_grid, 1 into ds_mask
__global__ __launch_bounds__(256) void scatter_kernel(const int* __restrict__ coords, int N,
                                                      const int* __restrict__ coords_ds, int M,
                                                      int* __restrict__ idx_grid,
                                                      unsigned char* __restrict__ ds_mask) {
    int i = blockIdx.x * 256 + threadIdx.x;
    if (i < N) {
        int a = coords[i * 3], b = coords[i * 3 + 1], c = coords[i * 3 + 2];
        idx_grid[(a * GD + b) * GD + c] = i;
    }
    if (i < M) {
        int a = coords_ds[i * 3], b = coords_ds[i * 3 + 1], c = coords_ds[i * 3 + 2];
        ds_mask[(a * GDS + b) * GDS + c] = 1;
    }
}

// ---------------------------------------------------------------------------
// pack conv1 weights: wpT[tap][oc][ic] (bf16) <- w_fuse[tap][ic][oc] (f32)
__global__ __launch_bounds__(256) void packw_kernel(const float* __restrict__ w,
                                                    ushort* __restrict__ wpT) {
    int i = blockIdx.x * 256 + threadIdx.x;  // 27*64*128
    if (i < 27 * 64 * 128) {
        int tap = i >> 13, oc = (i >> 7) & 63, ic = i & 127;
        wpT[i] = f2bf(w[tap * 8192 + ic * 64 + oc]);
    }
}

// fuse fc1||fref into bf16 rows [N+1][128]; row N = zeros (missing-neighbor row)
__global__ __launch_bounds__(256) void fusef_kernel(const float* __restrict__ fc1,
                                                    const float* __restrict__ fref, int N,
                                                    ushort* __restrict__ feats) {
    int i = blockIdx.x * 256 + threadIdx.x;  // (N+1)*128
    if (i < (N + 1) * 128) {
        int p = i >> 7, c = i & 127;
        float v = 0.f;
        if (p < N) v = (c < 64) ? fc1[p * 64 + c] : fref[p * 64 + c - 64];
        feats[i] = f2bf(v);
    }
}

// ---------------------------------------------------------------------------
// conv1 as implicit GEMM on MFMA: out[N,64] = relu(sum_tap X_tap[N,128]*W_tap[128,64] + b)
// Block: 64 points x 64 oc, 256 threads = 4 waves, each wave a 32x32 tile
// (2x2 fragments of mfma_f32_16x16x32_bf16).
// Staging: global_load_lds width-16, pre-swizzled source so LDS stays linear
// while logical layout carries the XOR swizzle (chunk ^= row&7) that makes the
// stride-256B ds_read_b128 fragment reads ~conflict-free (G4 / rule #21).
__global__ __launch_bounds__(256) void conv1_mfma(const int* __restrict__ coords, int N,
                                                  const ushort* __restrict__ feats,  // (N+1)x128
                                                  const ushort* __restrict__ wpT,    // 27x64x128
                                                  const float* __restrict__ b,       // 64
                                                  const int* __restrict__ idx_grid,
                                                  float* __restrict__ out /* N x 64 */) {
    __shared__ ushort xs[64 * 128];  // 16 KB, X rows (swizzled chunks)
    __shared__ ushort ws[64 * 128];  // 16 KB, W^T rows (swizzled chunks)
    __shared__ int nbr[64 * 27];
    __shared__ int pc[64 * 3];

    int tid = threadIdx.x;
    int p0 = blockIdx.x * 64;

    if (tid < 192) {
        int p = tid / 3, d = tid % 3;
        int gp = p0 + p;
        pc[tid] = (gp < N) ? coords[gp * 3 + d] : -1000;
    }
    __syncthreads();
    for (int t = tid; t < 64 * 27; t += 256) {
        int p = t / 27, tap = t % 27;
        int i = pc[p * 3 + 0] + tap / 9 - 1;
        int j = pc[p * 3 + 1] + (tap / 3) % 3 - 1;
        int k = pc[p * 3 + 2] + tap % 3 - 1;
        int nb = N;  // zero row
        if ((unsigned)i < (unsigned)GD && (unsigned)j < (unsigned)GD && (unsigned)k < (unsigned)GD) {
            int r = idx_grid[(i * GD + j) * GD + k];
            if (r >= 0) nb = r;
        }
        nbr[t] = nb;
    }

    int wid = tid >> 6, lane = tid & 63;
    int wm = wid >> 1, wn = wid & 1;  // wave tile origin: rows wm*32, cols wn*32
    int l16 = lane & 15, lq = lane >> 4;

    f32x4 acc[2][2] = {};

    for (int tap = 0; tap < 27; ++tap) {
        __syncthreads();  // previous tap's LDS reads done (and nbr ready at tap 0)
        // stage X: wave stages rows [wid*16, wid*16+16); 4 calls x 64 lanes x 16B
#pragma unroll
        for (int q = 0; q < 4; ++q) {
            int s = q * 64 + lane;            // linear slot in wave's 4KB region
            int pl = wid * 16 + (s >> 4);     // logical row 0..63
            int cs = s & 15;                  // linear chunk
            int c = cs ^ (pl & 7);            // logical chunk (inverse-swizzled source)
            int nb = nbr[pl * 27 + tap];
            const ushort* src = feats + (size_t)nb * 128 + c * 8;
            __builtin_amdgcn_global_load_lds(
                (const __attribute__((address_space(1))) unsigned int*)src,
                (__attribute__((address_space(3))) unsigned int*)(xs + wid * 2048 + q * 512),
                16, 0, 0);
        }
        // stage W^T rows likewise
#pragma unroll
        for (int q = 0; q < 4; ++q) {
            int s = q * 64 + lane;
            int r = wid * 16 + (s >> 4);
            int cs = s & 15;
            int c = cs ^ (r & 7);
            const ushort* src = wpT + tap * 8192 + r * 128 + c * 8;
            __builtin_amdgcn_global_load_lds(
                (const __attribute__((address_space(1))) unsigned int*)src,
                (__attribute__((address_space(3))) unsigned int*)(ws + wid * 2048 + q * 512),
                16, 0, 0);
        }
        __syncthreads();  // drains vmcnt: staged data visible
        // compute: K=128 in 4 steps of 32
#pragma unroll
        for (int k0 = 0; k0 < 4; ++k0) {
            int ca = k0 * 4 + lq;  // chunk holding this lane-quarter's 8 k-values
            bf16x8 a[2], bb[2];
#pragma unroll
            for (int mi = 0; mi < 2; ++mi) {
                int p = wm * 32 + mi * 16 + l16;
                a[mi] = *(const bf16x8*)(xs + p * 128 + (ca ^ (p & 7)) * 8);
            }
#pragma unroll
            for (int ni = 0; ni < 2; ++ni) {
                int r = wn * 32 + ni * 16 + l16;
                bb[ni] = *(const bf16x8*)(ws + r * 128 + (ca ^ (r & 7)) * 8);
            }
#pragma unroll
            for (int mi = 0; mi < 2; ++mi)
#pragma unroll
                for (int ni = 0; ni < 2; ++ni)
                    acc[mi][ni] = __builtin_amdgcn_mfma_f32_16x16x32_bf16(a[mi], bb[ni],
                                                                          acc[mi][ni], 0, 0, 0);
        }
    }
    // epilogue: D layout col=lane&15, row=(lane>>4)*4+j  (m89-verified)
#pragma unroll
    for (int ni = 0; ni < 2; ++ni) {
        int ocol = wn * 32 + ni * 16 + l16;
        float bias = b[ocol];
#pragma unroll
        for (int mi = 0; mi < 2; ++mi) {
#pragma unroll
            for (int j = 0; j < 4; ++j) {
                int p = p0 + wm * 32 + mi * 16 + lq * 4 + j;
                if (p < N) {
                    float v = acc[mi][ni][j] + bias;
                    out[(size_t)p * 64 + ocol] = v > 0.f ? v : 0.f;
                }
            }
        }
    }
}

// ---------------------------------------------------------------------------
// down: 2x2x2 stride-2 VALID, 64 -> 64, input = sparse feats1 via idx_grid,
// output dense 32^3 x 64 (0 at masked-out sites). Block = 8 ds-sites.
__global__ __launch_bounds__(256) void down_kernel(const float* __restrict__ feats1,
                                                   const int* __restrict__ idx_grid,
                                                   const float* __restrict__ w,  // 8*64*64
                                                   const float* __restrict__ b,
                                                   const unsigned char* __restrict__ ds_mask,
                                                   float* __restrict__ out /* 32^3 x 64 */) {
    __shared__ float xs[8 * 8 * 64];
    __shared__ float wt[64 * 64];
    int tid = threadIdx.x;
    int s0 = blockIdx.x * 8;

    for (int idx = tid; idx < 8 * 8 * 64; idx += 256) {
        int s_l = idx >> 9, t = (idx >> 6) & 7, ic = idx & 63;
        int s = s0 + s_l;
        int i = s >> 10, j = (s >> 5) & 31, k = s & 31;
        int ci = 2 * i + (t >> 2), cj = 2 * j + ((t >> 1) & 1), ck = 2 * k + (t & 1);
        int r = idx_grid[(ci * GD + cj) * GD + ck];
        xs[idx] = (r >= 0) ? feats1[(size_t)r * 64 + ic] : 0.f;
    }

    int oc = tid & 63, sg = tid >> 6;
    float acc[2] = {0.f, 0.f};
    for (int t = 0; t < 8; ++t) {
        __syncthreads();
        for (int idx = tid; idx < 4096; idx += 256) wt[idx] = w[t * 4096 + idx];
        __syncthreads();
        for (int ic = 0; ic < 64; ic += 4) {
            float w0 = wt[(ic + 0) * 64 + oc], w1 = wt[(ic + 1) * 64 + oc];
            float w2 = wt[(ic + 2) * 64 + oc], w3 = wt[(ic + 3) * 64 + oc];
#pragma unroll
            for (int q = 0; q < 2; ++q) {
                const float4 xv = *(const float4*)&xs[((sg * 2 + q) * 8 + t) * 64 + ic];
                acc[q] += xv.x * w0 + xv.y * w1 + xv.z * w2 + xv.w * w3;
            }
        }
    }
    float bias = b[oc];
#pragma unroll
    for (int q = 0; q < 2; ++q) {
        int s = s0 + sg * 2 + q;
        float v = 0.f;
        if (ds_mask[s]) {
            v = acc[q] + bias;
            v = v > 0.f ? v : 0.f;
        }
        out[(size_t)s * 64 + oc] = v;
    }
}

// ---------------------------------------------------------------------------
// Generic masked conv on the dense 32^3 grid. KS in {1,3}. Fused bias, relu,
// mask (write 0 at masked-out sites), optional residual add (res stride 64),
// output channel offset (implements the concat) and output stride.
template <int CIN, int COUT, int KS, bool RELU, bool HASRES>
__global__ __launch_bounds__(256) void sconv_kernel(const float* __restrict__ in,  // 32^3 x CIN
                                                    const float* __restrict__ w,   // KS^3*CIN*COUT
                                                    const float* __restrict__ b,   // COUT
                                                    const unsigned char* __restrict__ ds_mask,
                                                    const float* __restrict__ res,  // 32^3 x 64
                                                    float* __restrict__ out, int ostride, int ooff) {
    constexpr int T = KS * KS * KS;
    constexpr int NS = COUT / 16;  // sites per thread (block covers 16 sites)
    constexpr int XROW = CIN + 4;  // pad to spread banks, keeps 16B alignment
    __shared__ float xs[16 * XROW];
    __shared__ float wt[CIN * COUT];

    int tid = threadIdx.x;
    int s0 = blockIdx.x * 16;
    int i0 = s0 >> 10, j0 = (s0 >> 5) & 31, k0 = s0 & 31;
    int oc = tid % COUT, sg = tid / COUT;

    float acc[NS];
#pragma unroll
    for (int q = 0; q < NS; ++q) acc[q] = 0.f;

    for (int tap = 0; tap < T; ++tap) {
        int dz = (KS == 3) ? tap / 9 - 1 : 0;
        int dy = (KS == 3) ? (tap / 3) % 3 - 1 : 0;
        int dx = (KS == 3) ? tap % 3 - 1 : 0;
        __syncthreads();
        for (int idx = tid; idx < CIN * COUT; idx += 256) wt[idx] = w[tap * CIN * COUT + idx];
        int ni = i0 + dz, nj = j0 + dy;
        bool rowok = ((unsigned)ni < (unsigned)GDS) && ((unsigned)nj < (unsigned)GDS);
        for (int idx = tid; idx < 16 * CIN; idx += 256) {
            int s_l = idx / CIN, ic = idx % CIN;
            int nk = k0 + s_l + dx;
            float v = 0.f;
            if (rowok && (unsigned)nk < (unsigned)GDS)
                v = in[(size_t)((ni * GDS + nj) * GDS + nk) * CIN + ic];
            xs[s_l * XROW + ic] = v;
        }
        __syncthreads();
        for (int ic = 0; ic < CIN; ic += 4) {
            float w0 = wt[(ic + 0) * COUT + oc], w1 = wt[(ic + 1) * COUT + oc];
            float w2 = wt[(ic + 2) * COUT + oc], w3 = wt[(ic + 3) * COUT + oc];
#pragma unroll
            for (int q = 0; q < NS; ++q) {
                const float4 xv = *(const float4*)&xs[(sg * NS + q) * XROW + ic];
                acc[q] += xv.x * w0 + xv.y * w1 + xv.z * w2 + xv.w * w3;
            }
        }
    }
    float bias = b[oc];
#pragma unroll
    for (int q = 0; q < NS; ++q) {
        int s = s0 + sg * NS + q;
        float v = 0.f;
        if (ds_mask[s]) {
            v = acc[q] + bias;
            if (RELU) v = v > 0.f ? v : 0.f;
        }
        if (HASRES) v += res[(size_t)s * 64 + ooff + oc];
        out[(size_t)s * ostride + ooff + oc] = v;
    }
}

// final gather: out[m][oc] = x[ds_site(m)][oc]
__global__ __launch_bounds__(256) void gather_kernel(const float* __restrict__ x,
                                                     const int* __restrict__ coords_ds, int M,
                                                     float* __restrict__ out) {
    int i = blockIdx.x * 256 + threadIdx.x;
    if (i < M * 64) {
        int m = i >> 6, oc = i & 63;
        int a = coords_ds[m * 3], b = coords_ds[m * 3 + 1], c = coords_ds[m * 3 + 2];
        out[i] = x[((size_t)((a * GDS + b) * GDS + c) << 6) + oc];
    }
}

// ---------------------------------------------------------------------------
extern "C" void kernel_launch(void* const* d_in, const int* in_sizes, int n_in,
                              void* d_out, int out_size, void* d_ws, size_t ws_size,
                              hipStream_t stream) {
    const int* coords = (const int*)d_in[0];
    const int* coords_ds = (const int*)d_in[1];
    const float* fc1 = (const float*)d_in[2];
    const float* fref = (const float*)d_in[3];
    const float* w_fuse = (const float*)d_in[4];
    const float* b_fuse = (const float*)d_in[5];
    const float* w_down = (const float*)d_in[6];
    const float* b_down = (const float*)d_in[7];
    const float* w_conv2 = (const float*)d_in[8];
    const float* b_conv2 = (const float*)d_in[9];
    const float* w_p00 = (const float*)d_in[10];
    const float* b_p00 = (const float*)d_in[11];
    const float* w_p01 = (const float*)d_in[12];
    const float* b_p01 = (const float*)d_in[13];
    const float* w_p10 = (const float*)d_in[14];
    const float* b_p10 = (const float*)d_in[15];
    const float* w_p11 = (const float*)d_in[16];
    const float* b_p11 = (const float*)d_in[17];
    const float* w_p12 = (const float*)d_in[18];
    const float* b_p12 = (const float*)d_in[19];

    const int N = in_sizes[0] / 3;
    const int M = in_sizes[1] / 3;
    const int L = in_sizes[10] / (27 * 64 * 16);
    const int NSITES = GDS * GDS * GDS;  // 32768

    // workspace carve-up (~74 MB)
    size_t off = 0;
    auto alloc = [&](size_t bytes) {
        void* p = (char*)d_ws + off;
        off += (bytes + 255) & ~(size_t)255;
        return p;
    };
    int* idx_grid = (int*)alloc((size_t)GD * GD * GD * 4);
    unsigned char* ds_mask = (unsigned char*)alloc(NSITES);
    float* feats1 = (float*)alloc((size_t)N * 64 * 4);
    float* xA = (float*)alloc((size_t)NSITES * 64 * 4);
    float* xB = (float*)alloc((size_t)NSITES * 64 * 4);
    float* t16a = (float*)alloc((size_t)NSITES * 16 * 4);
    float* t16b = (float*)alloc((size_t)NSITES * 16 * 4);
    ushort* wpT = (ushort*)alloc((size_t)27 * 64 * 128 * 2);
    ushort* featsB = (ushort*)alloc((size_t)(N + 1) * 128 * 2);
    (void)ws_size;

    float* out = (float*)d_out;
    (void)out_size; (void)n_in;

    init_kernel<<<(GD * GD * GD) / 256, 256, 0, stream>>>(idx_grid, ds_mask);
    {
        int mx = N > M ? N : M;
        scatter_kernel<<<(mx + 255) / 256, 256, 0, stream>>>(coords, N, coords_ds, M, idx_grid,
                                                             ds_mask);
    }
    packw_kernel<<<(27 * 64 * 128 + 255) / 256, 256, 0, stream>>>(w_fuse, wpT);
    fusef_kernel<<<((N + 1) * 128 + 255) / 256, 256, 0, stream>>>(fc1, fref, N, featsB);
    conv1_mfma<<<(N + 63) / 64, 256, 0, stream>>>(coords, N, featsB, wpT, b_fuse, idx_grid,
                                                  feats1);
    down_kernel<<<NSITES / 8, 256, 0, stream>>>(feats1, idx_grid, w_down, b_down, ds_mask, xB);
    sconv_kernel<64, 64, 3, false, false>
        <<<NSITES / 16, 256, 0, stream>>>(xB, w_conv2, b_conv2, ds_mask, nullptr, xA, 64, 0);

    float* x = xA;
    float* y = xB;
    for (int i = 0; i < L; ++i) {
        const float* wp00 = w_p00 + (size_t)i * 27 * 64 * 16;
        const float* bp00 = b_p00 + (size_t)i * 16;
        const float* wp01 = w_p01 + (size_t)i * 27 * 16 * 32;
        const float* bp01 = b_p01 + (size_t)i * 32;
        const float* wp10 = w_p10 + (size_t)i * 64 * 16;
        const float* bp10 = b_p10 + (size_t)i * 16;
        const float* wp11 = w_p11 + (size_t)i * 27 * 16 * 16;
        const float* bp11 = b_p11 + (size_t)i * 16;
        const float* wp12 = w_p12 + (size_t)i * 16 * 32;
        const float* bp12 = b_p12 + (size_t)i * 32;

        // p0 = relu(conv3(x, w00)); p0 = conv3(p0, w01) -> y[:,0:32] += x[:,0:32]
        sconv_kernel<64, 16, 3, true, false>
            <<<NSITES / 16, 256, 0, stream>>>(x, wp00, bp00, ds_mask, nullptr, t16a, 16, 0);
        sconv_kernel<16, 32, 3, false, true>
            <<<NSITES / 16, 256, 0, stream>>>(t16a, wp01, bp01, ds_mask, x, y, 64, 0);
        // p1 = relu(conv1(x, w10)); p1 = relu(conv3(p1, w11)); p1 = conv1(p1, w12)
        //   -> y[:,32:64] += x[:,32:64]
        sconv_kernel<64, 16, 1, true, false>
            <<<NSITES / 16, 256, 0, stream>>>(x, wp10, bp10, ds_mask, nullptr, t16b, 16, 0);
        sconv_kernel<16, 16, 3, true, false>
            <<<NSITES / 16, 256, 0, stream>>>(t16b, wp11, bp11, ds_mask, nullptr, t16a, 16, 0);
        sconv_kernel<16, 32, 1, false, true>
            <<<NSITES / 16, 256, 0, stream>>>(t16a, wp12, bp12, ds_mask, x, y, 64, 32);
        // swap ping-pong
        float* tmp = x; x = y; y = tmp;
    }

    gather_kernel<<<(M * 64 + 255) / 256, 256, 0, stream>>>(x, coords_ds, M, out);
}

// Round 4
// 436.682 us; speedup vs baseline: 5.0263x; 2.5428x over previous
//
#include <hip/hip_runtime.h>

// Sizes fixed by the reference: C=64, D=64 grid, ds grid 32^3.
#define GD 64
#define GDS 32

typedef _Float16 f16;
typedef __attribute__((ext_vector_type(8))) _Float16 f16x8;
typedef __attribute__((ext_vector_type(4))) float f32x4;

#define GLOAD_LDS16(SRC, DST)                                                        \
    __builtin_amdgcn_global_load_lds(                                                \
        (const __attribute__((address_space(1))) unsigned int*)(const void*)(SRC),   \
        (__attribute__((address_space(3))) unsigned int*)(void*)(DST), 16, 0, 0)

// ---------------------------------------------------------------------------
// init: idx_grid=-1, ds_mask=0, zrow=0 (zero 16B-source), feats1h zero row
__global__ __launch_bounds__(256) void init_kernel(int* __restrict__ idx_grid,
                                                   unsigned char* __restrict__ ds_mask,
                                                   f16* __restrict__ zrow,
                                                   f16* __restrict__ f1z) {
    int i = blockIdx.x * 256 + threadIdx.x;
    if (i < GD * GD * GD) idx_grid[i] = -1;
    if (i < GDS * GDS * GDS) ds_mask[i] = 0;
    if (i < 128) zrow[i] = (f16)0.f;
    if (i < 64) f1z[i] = (f16)0.f;
}

__global__ __launch_bounds__(256) void scatter_kernel(const int* __restrict__ coords, int N,
                                                      const int* __restrict__ coords_ds, int M,
                                                      int* __restrict__ idx_grid,
                                                      unsigned char* __restrict__ ds_mask) {
    int i = blockIdx.x * 256 + threadIdx.x;
    if (i < N) {
        int a = coords[i * 3], b = coords[i * 3 + 1], c = coords[i * 3 + 2];
        idx_grid[(a * GD + b) * GD + c] = i;
    }
    if (i < M) {
        int a = coords_ds[i * 3], b = coords_ds[i * 3 + 1], c = coords_ds[i * 3 + 2];
        ds_mask[(a * GDS + b) * GDS + c] = 1;
    }
}

// ---------------------------------------------------------------------------
// pack all weights to f16 [tap][oc][ic] layouts (+ fused bias arrays, f32)
__global__ __launch_bounds__(256) void pack_kernel(
    const float* __restrict__ wf, const float* __restrict__ wd, const float* __restrict__ wc2,
    const float* __restrict__ wp00, const float* __restrict__ wp01, const float* __restrict__ wp10,
    const float* __restrict__ wp11, const float* __restrict__ wp12, const float* __restrict__ bp00,
    const float* __restrict__ bp01, const float* __restrict__ bp10, const float* __restrict__ bp11,
    int L, f16* __restrict__ wc1, f16* __restrict__ wdnh, f16* __restrict__ wc2h,
    f16* __restrict__ wfA, f16* __restrict__ wfB, f16* __restrict__ w12h, float* __restrict__ bA,
    float* __restrict__ bB) {
    int i = blockIdx.x * 256 + threadIdx.x;
    int n;
    n = 27 * 8192;
    if (i < n) {
        int tap = i >> 13, oc = (i >> 7) & 63, ic = i & 127;
        wc1[i] = (f16)wf[(tap * 128 + ic) * 64 + oc];
        return;
    }
    i -= n;
    n = 8 * 4096;
    if (i < n) {
        int t = i >> 12, oc = (i >> 6) & 63, ic = i & 63;
        wdnh[i] = (f16)wd[(t * 64 + ic) * 64 + oc];
        return;
    }
    i -= n;
    n = 27 * 4096;
    if (i < n) {
        int tap = i >> 12, oc = (i >> 6) & 63, ic = i & 63;
        wc2h[i] = (f16)wc2[(tap * 64 + ic) * 64 + oc];
        return;
    }
    i -= n;
    n = L * 27 * 2048;
    if (i < n) {  // wfA: [l][tap][oc(32)][ic(64)]; oc<16: w_p00, oc>=16: center-tap w_p10
        int l = i / (27 * 2048), r = i - l * 27 * 2048;
        int tap = r >> 11, oc = (r >> 6) & 31, ic = r & 63;
        float v = 0.f;
        if (oc < 16) v = wp00[(((size_t)l * 27 + tap) * 64 + ic) * 16 + oc];
        else if (tap == 13) v = wp10[((size_t)l * 64 + ic) * 16 + (oc - 16)];
        wfA[i] = (f16)v;
        return;
    }
    i -= n;
    n = L * 27 * 1536;
    if (i < n) {  // wfB: [l][tap][oc(48)][ic(32)]; oc<32: w_p01 (ic<16), oc>=32: w_p11 (ic>=16)
        int l = i / (27 * 1536), r = i - l * 27 * 1536;
        int tap = r / 1536, q = r - tap * 1536;
        int oc = q >> 5, ic = q & 31;
        float v = 0.f;
        if (oc < 32) {
            if (ic < 16) v = wp01[(((size_t)l * 27 + tap) * 16 + ic) * 32 + oc];
        } else {
            if (ic >= 16) v = wp11[(((size_t)l * 27 + tap) * 16 + (ic - 16)) * 16 + (oc - 32)];
        }
        wfB[i] = (f16)v;
        return;
    }
    i -= n;
    n = L * 512;
    if (i < n) {
        int l = i >> 9, q = i & 511, oc = q >> 4, ic = q & 15;
        w12h[i] = (f16)wp12[((size_t)l * 16 + ic) * 32 + oc];
        return;
    }
    i -= n;
    n = L * 32;
    if (i < n) {
        int l = i >> 5, oc = i & 31;
        bA[i] = (oc < 16) ? bp00[l * 16 + oc] : bp10[l * 16 + oc - 16];
        return;
    }
    i -= n;
    n = L * 48;
    if (i < n) {
        int l = i / 48, c = i - l * 48;
        bB[i] = (c < 32) ? bp01[l * 32 + c] : bp11[l * 16 + (c - 32)];
    }
}

// fuse fc1||fref into f16 rows [N+1][128]; row N = zeros
__global__ __launch_bounds__(256) void fusef_kernel(const float* __restrict__ fc1,
                                                    const float* __restrict__ fref, int N,
                                                    f16* __restrict__ feats) {
    int i = blockIdx.x * 256 + threadIdx.x;
    if (i < (N + 1) * 128) {
        int p = i >> 7, c = i & 127;
        float v = 0.f;
        if (p < N) v = (c < 64) ? fc1[p * 64 + c] : fref[p * 64 + c - 64];
        feats[i] = (f16)v;
    }
}

// ---------------------------------------------------------------------------
// conv1: implicit GEMM, 128 points x 64 oc per block, 8 waves (4m x 2n) of 32x32.
// X double-buffered in LDS (1 barrier/tap, prefetch overlapped); W direct from L2.
__global__ __launch_bounds__(512) void conv1_mfma(const int* __restrict__ coords, int N,
                                                  const f16* __restrict__ featsB,  // (N+1)x128
                                                  const f16* __restrict__ wc1,     // 27x64x128
                                                  const float* __restrict__ bias,
                                                  const int* __restrict__ idx_grid,
                                                  f16* __restrict__ out /* (N+1) x 64 */) {
    __shared__ f16 xs[2][128 * 128];
    __shared__ int nbr[128 * 27];
    __shared__ int pc[128 * 3];
    const int tid = threadIdx.x;
    const int p0b = blockIdx.x * 128;

    if (tid < 384) {
        int p = tid / 3, d = tid - p * 3;
        int gp = p0b + p;
        pc[tid] = (gp < N) ? coords[gp * 3 + d] : -1000;
    }
    __syncthreads();
    for (int t = tid; t < 128 * 27; t += 512) {
        int p = t / 27, tap = t - p * 27;
        int i = pc[p * 3 + 0] + tap / 9 - 1;
        int j = pc[p * 3 + 1] + (tap / 3) % 3 - 1;
        int k = pc[p * 3 + 2] + tap % 3 - 1;
        int nb = N;
        if ((unsigned)i < (unsigned)GD && (unsigned)j < (unsigned)GD && (unsigned)k < (unsigned)GD) {
            int r = idx_grid[(i * GD + j) * GD + k];
            if (r >= 0) nb = r;
        }
        nbr[t] = nb;
    }
    __syncthreads();

    auto stage = [&](int tap, int buf) {
#pragma unroll
        for (int rr = 0; rr < 4; ++rr) {
            int slot = rr * 512 + tid;
            int row = slot >> 4, cl = slot & 15;
            int c = cl ^ (row & 7);
            const f16* src = featsB + (size_t)nbr[row * 27 + tap] * 128 + c * 8;
            f16* dst = &xs[buf][0] + (size_t)(rr * 512 + (tid & ~63)) * 8;
            GLOAD_LDS16(src, dst);
        }
    };

    const int lane = tid & 63, wid = tid >> 6;
    const int l16 = lane & 15, lq = lane >> 4;
    const int wm = wid >> 1, wn = wid & 1;
    const int m0 = wm * 32, n0 = wn * 32;
    f32x4 acc[2][2] = {};

    stage(0, 0);
    __syncthreads();
    for (int tap = 0; tap < 27; ++tap) {
        if (tap < 26) stage(tap + 1, (tap + 1) & 1);
        const f16* xb = &xs[tap & 1][0];
        f16x8 a[2][4], bfr[2][4];
#pragma unroll
        for (int mi = 0; mi < 2; ++mi) {
            int row = m0 + mi * 16 + l16;
#pragma unroll
            for (int ks = 0; ks < 4; ++ks) {
                int ch = ks * 4 + lq;
                a[mi][ks] = *(const f16x8*)(xb + (size_t)row * 128 + (ch ^ (row & 7)) * 8);
            }
        }
#pragma unroll
        for (int ni = 0; ni < 2; ++ni) {
            int col = n0 + ni * 16 + l16;
#pragma unroll
            for (int ks = 0; ks < 4; ++ks)
                bfr[ni][ks] =
                    *(const f16x8*)(wc1 + (size_t)((tap * 64 + col) * 128 + (ks * 4 + lq) * 8));
        }
#pragma unroll
        for (int mi = 0; mi < 2; ++mi)
#pragma unroll
            for (int ni = 0; ni < 2; ++ni)
#pragma unroll
                for (int ks = 0; ks < 4; ++ks)
                    acc[mi][ni] = __builtin_amdgcn_mfma_f32_16x16x32_f16(a[mi][ks], bfr[ni][ks],
                                                                         acc[mi][ni], 0, 0, 0);
        __syncthreads();
    }
#pragma unroll
    for (int ni = 0; ni < 2; ++ni) {
        int col = n0 + ni * 16 + l16;
        float bv = bias[col];
#pragma unroll
        for (int mi = 0; mi < 2; ++mi) {
#pragma unroll
            for (int j = 0; j < 4; ++j) {
                int p = p0b + m0 + mi * 16 + lq * 4 + j;
                if (p < N) {
                    float v = acc[mi][ni][j] + bv;
                    out[(size_t)p * 64 + col] = (f16)(v > 0.f ? v : 0.f);
                }
            }
        }
    }
}

// ---------------------------------------------------------------------------
// down: 2x2x2 stride-2, gather-MFMA. 128 ds-sites/block, 8 taps, dbuf staging.
__global__ __launch_bounds__(512) void down_mfma(const f16* __restrict__ feats1h, int N,
                                                 const int* __restrict__ idx_grid,
                                                 const f16* __restrict__ wdn,  // 8x64x64
                                                 const float* __restrict__ bias,
                                                 const unsigned char* __restrict__ mask,
                                                 f16* __restrict__ out /* 32768 x 64 */) {
    __shared__ f16 xs[2][128 * 64];
    __shared__ int nbr[128 * 8];
    const int tid = threadIdx.x;
    const int s0 = blockIdx.x * 128;
    for (int t = tid; t < 128 * 8; t += 512) {
        int sl = t >> 3, tp = t & 7;
        int s = s0 + sl;
        int i = s >> 10, j = (s >> 5) & 31, k = s & 31;
        int ci = 2 * i + (tp >> 2), cj = 2 * j + ((tp >> 1) & 1), ck = 2 * k + (tp & 1);
        int r = idx_grid[(ci * GD + cj) * GD + ck];
        nbr[t] = (r >= 0) ? r : N;
    }
    __syncthreads();
    auto stage = [&](int tp, int buf) {
#pragma unroll
        for (int rr = 0; rr < 2; ++rr) {
            int slot = rr * 512 + tid;
            int row = slot >> 3, cl = slot & 7;
            int c = cl ^ (row & 7);
            const f16* src = feats1h + (size_t)nbr[row * 8 + tp] * 64 + c * 8;
            f16* dst = &xs[buf][0] + (size_t)(rr * 512 + (tid & ~63)) * 8;
            GLOAD_LDS16(src, dst);
        }
    };
    const int lane = tid & 63, wid = tid >> 6;
    const int l16 = lane & 15, lq = lane >> 4;
    const int wm = wid >> 1, wn = wid & 1;
    const int m0 = wm * 32, n0 = wn * 32;
    f32x4 acc[2][2] = {};
    stage(0, 0);
    __syncthreads();
    for (int tp = 0; tp < 8; ++tp) {
        if (tp < 7) stage(tp + 1, (tp + 1) & 1);
        const f16* xb = &xs[tp & 1][0];
        f16x8 a[2][2], bfr[2][2];
#pragma unroll
        for (int mi = 0; mi < 2; ++mi) {
            int row = m0 + mi * 16 + l16;
#pragma unroll
            for (int ks = 0; ks < 2; ++ks) {
                int ch = ks * 4 + lq;
                a[mi][ks] = *(const f16x8*)(xb + (size_t)row * 64 + (ch ^ (row & 7)) * 8);
            }
        }
#pragma unroll
        for (int ni = 0; ni < 2; ++ni) {
            int col = n0 + ni * 16 + l16;
#pragma unroll
            for (int ks = 0; ks < 2; ++ks)
                bfr[ni][ks] =
                    *(const f16x8*)(wdn + (size_t)((tp * 64 + col) * 64 + (ks * 4 + lq) * 8));
        }
#pragma unroll
        for (int mi = 0; mi < 2; ++mi)
#pragma unroll
            for (int ni = 0; ni < 2; ++ni)
#pragma unroll
                for (int ks = 0; ks < 2; ++ks)
                    acc[mi][ni] = __builtin_amdgcn_mfma_f32_16x16x32_f16(a[mi][ks], bfr[ni][ks],
                                                                         acc[mi][ni], 0, 0, 0);
        __syncthreads();
    }
#pragma unroll
    for (int mi = 0; mi < 2; ++mi) {
        int m = m0 + mi * 16 + lq * 4;
        int site = s0 + m;
        unsigned mword = *(const unsigned*)(mask + site);
#pragma unroll
        for (int ni = 0; ni < 2; ++ni) {
            int col = n0 + ni * 16 + l16;
            float bv = bias[col];
#pragma unroll
            for (int j = 0; j < 4; ++j) {
                float v = 0.f;
                if ((mword >> (8 * j)) & 255) {
                    v = acc[mi][ni][j] + bv;
                    v = v > 0.f ? v : 0.f;
                }
                out[(size_t)(site + j) * 64 + col] = (f16)v;
            }
        }
    }
}

// ---------------------------------------------------------------------------
// Generic dense 32^3 masked conv (27 taps), f16 MFMA. Block = 128 sites
// (4 k-pencils at (i0, j0..j0+3)), 512 threads / 8 waves. Full halo (18
// pencils, k-padded, XOR-swizzled) staged ONCE in LDS; tap loop barrier-free;
// B-fragments direct from global (L2-resident). RELUFROM: relu for col>=RELUFROM.
template <int CIN, int COUT, int NW, int RELUFROM>
__global__ __launch_bounds__(512) void dconv_kernel(const f16* __restrict__ x,
                                                    const f16* __restrict__ wp,  // 27 x COUT x CIN
                                                    const float* __restrict__ bias,
                                                    const unsigned char* __restrict__ mask,
                                                    const f16* __restrict__ zrow,
                                                    f16* __restrict__ out /* 32768 x COUT */) {
    constexpr int NCH = CIN / 8;          // 16B chunks per row
    constexpr int PSLOT = 34 * NCH;       // slots per pencil (k = -1..32)
    constexpr int STOT = 18 * PSLOT;      // total halo slots
    constexpr int RNDS = (STOT + 511) / 512;
    constexpr int MW = 8 / NW;
    constexpr int WM = 128 / MW, WN = COUT / NW;
    constexpr int FM = WM / 16, FN = WN / 16, KS = CIN / 32;
    __shared__ f16 xs[RNDS * 512 * 8];

    const int tid = threadIdx.x;
    const int bid = blockIdx.x;
    const int i0 = bid >> 3, j0 = (bid & 7) * 4;

    // stage halo: 18 pencils x 34 rows (pad rows & OOB pencils <- zrow)
    for (int rr = 0; rr < RNDS; ++rr) {
        int slot = rr * 512 + tid;
        int p = slot / PSLOT;
        int rem = slot - p * PSLOT;
        int r = rem / NCH;
        int cl = rem - r * NCH;
        int c = cl ^ (r & (NCH - 1));
        int gi = i0 + p / 6 - 1, gj = j0 + p % 6 - 1, gk = r - 1;
        bool ok = (slot < STOT) && ((unsigned)gi < 32u) && ((unsigned)gj < 32u) &&
                  ((unsigned)gk < 32u);
        const f16* src = ok ? (x + (size_t)(((gi * 32 + gj) * 32 + gk) * CIN + c * 8)) : zrow;
        f16* dst = xs + (size_t)(rr * 512 + (tid & ~63)) * 8;
        GLOAD_LDS16(src, dst);
    }
    __syncthreads();

    const int lane = tid & 63, wid = tid >> 6;
    const int l16 = lane & 15, lq = lane >> 4;
    const int wm = wid / NW, wn = wid - wm * NW;
    const int m0 = wm * WM, n0 = wn * WN;

    f32x4 acc[FM][FN] = {};

    for (int tap = 0; tap < 27; ++tap) {
        int di = tap / 9 - 1, dj = (tap / 3) % 3 - 1, dk = tap % 3 - 1;
        f16x8 a[FM][KS], bfr[FN][KS];
#pragma unroll
        for (int mi = 0; mi < FM; ++mi) {
            int m = m0 + mi * 16 + l16;
            int pj = m >> 5, k = m & 31;
            int p = (di + 1) * 6 + (pj + dj + 1);
            int r = k + dk + 1;
#pragma unroll
            for (int ks = 0; ks < KS; ++ks) {
                int ch = ks * 4 + lq;
                a[mi][ks] =
                    *(const f16x8*)(xs + (size_t)(p * PSLOT + r * NCH + (ch ^ (r & (NCH - 1)))) * 8);
            }
        }
#pragma unroll
        for (int ni = 0; ni < FN; ++ni) {
            int col = n0 + ni * 16 + l16;
#pragma unroll
            for (int ks = 0; ks < KS; ++ks)
                bfr[ni][ks] =
                    *(const f16x8*)(wp + (size_t)((tap * COUT + col) * CIN + (ks * 4 + lq) * 8));
        }
#pragma unroll
        for (int mi = 0; mi < FM; ++mi)
#pragma unroll
            for (int ni = 0; ni < FN; ++ni)
#pragma unroll
                for (int ks = 0; ks < KS; ++ks)
                    acc[mi][ni] = __builtin_amdgcn_mfma_f32_16x16x32_f16(a[mi][ks], bfr[ni][ks],
                                                                         acc[mi][ni], 0, 0, 0);
    }

#pragma unroll
    for (int mi = 0; mi < FM; ++mi) {
        int m = m0 + mi * 16 + lq * 4;
        int pj = m >> 5, k = m & 31;
        int gsite = ((i0 * 32) + (j0 + pj)) * 32 + k;
        unsigned mword = *(const unsigned*)(mask + gsite);
#pragma unroll
        for (int ni = 0; ni < FN; ++ni) {
            int col = n0 + ni * 16 + l16;
            float bv = bias[col];
#pragma unroll
            for (int j = 0; j < 4; ++j) {
                float v = 0.f;
                if ((mword >> (8 * j)) & 255) {
                    v = acc[mi][ni][j] + bv;
                    if (col >= RELUFROM) v = v > 0.f ? v : 0.f;
                }
                out[(size_t)(gsite + j) * COUT + col] = (f16)v;
            }
        }
    }
}

// ---------------------------------------------------------------------------
// tail: p1 = (u1 . w12 + b12)*mask; y = [p0 + x_lo | p1 + x_hi]. One thread/site.
template <typename OUTT>
__global__ __launch_bounds__(256) void tail_kernel(const f16* __restrict__ ph,   // 32768 x 48
                                                   const f16* __restrict__ xh,   // 32768 x 64
                                                   const f16* __restrict__ w12,  // 32 x 16
                                                   const float* __restrict__ b12,
                                                   const unsigned char* __restrict__ mask,
                                                   OUTT* __restrict__ y /* 32768 x 64 */) {
    __shared__ float ws[512];
    __shared__ float bs[32];
    int tid = threadIdx.x;
    ws[tid] = (float)w12[tid];
    ws[tid + 256] = (float)w12[tid + 256];
    if (tid < 32) bs[tid] = b12[tid];
    __syncthreads();
    int site = blockIdx.x * 256 + tid;
    const f16* pr = ph + (size_t)site * 48;
    const f16* xr = xh + (size_t)site * 64;
    float u1[16];
#pragma unroll
    for (int ic = 0; ic < 16; ++ic) u1[ic] = (float)pr[32 + ic];
    bool mk = mask[site] != 0;
    float yv[64];
#pragma unroll
    for (int c = 0; c < 32; ++c) yv[c] = (float)pr[c] + (float)xr[c];
#pragma unroll
    for (int oc = 0; oc < 32; ++oc) {
        float s = 0.f;
#pragma unroll
        for (int ic = 0; ic < 16; ++ic) s += u1[ic] * ws[oc * 16 + ic];
        float p1 = mk ? (s + bs[oc]) : 0.f;
        yv[32 + oc] = p1 + (float)xr[32 + oc];
    }
#pragma unroll
    for (int c = 0; c < 64; ++c) y[(size_t)site * 64 + c] = (OUTT)yv[c];
}

// final gather: out[m][oc] = xF[ds_site(m)][oc]
__global__ __launch_bounds__(256) void gather_kernel(const float* __restrict__ x,
                                                     const int* __restrict__ coords_ds, int M,
                                                     float* __restrict__ out) {
    int i = blockIdx.x * 256 + threadIdx.x;
    if (i < M * 64) {
        int m = i >> 6, oc = i & 63;
        int a = coords_ds[m * 3], b = coords_ds[m * 3 + 1], c = coords_ds[m * 3 + 2];
        out[i] = x[((size_t)((a * GDS + b) * GDS + c) << 6) + oc];
    }
}

// ---------------------------------------------------------------------------
extern "C" void kernel_launch(void* const* d_in, const int* in_sizes, int n_in,
                              void* d_out, int out_size, void* d_ws, size_t ws_size,
                              hipStream_t stream) {
    const int* coords = (const int*)d_in[0];
    const int* coords_ds = (const int*)d_in[1];
    const float* fc1 = (const float*)d_in[2];
    const float* fref = (const float*)d_in[3];
    const float* w_fuse = (const float*)d_in[4];
    const float* b_fuse = (const float*)d_in[5];
    const float* w_down = (const float*)d_in[6];
    const float* b_down = (const float*)d_in[7];
    const float* w_conv2 = (const float*)d_in[8];
    const float* b_conv2 = (const float*)d_in[9];
    const float* w_p00 = (const float*)d_in[10];
    const float* b_p00 = (const float*)d_in[11];
    const float* w_p01 = (const float*)d_in[12];
    const float* b_p01 = (const float*)d_in[13];
    const float* w_p10 = (const float*)d_in[14];
    const float* b_p10 = (const float*)d_in[15];
    const float* w_p11 = (const float*)d_in[16];
    const float* b_p11 = (const float*)d_in[17];
    const float* w_p12 = (const float*)d_in[18];
    const float* b_p12 = (const float*)d_in[19];

    const int N = in_sizes[0] / 3;
    const int M = in_sizes[1] / 3;
    const int L = in_sizes[10] / (27 * 64 * 16);
    const int NSITES = GDS * GDS * GDS;  // 32768

    size_t off = 0;
    auto alloc = [&](size_t bytes) {
        void* p = (char*)d_ws + off;
        off += (bytes + 255) & ~(size_t)255;
        return p;
    };
    int* idx_grid = (int*)alloc((size_t)GD * GD * GD * 4);
    unsigned char* ds_mask = (unsigned char*)alloc(NSITES);
    f16* zrow = (f16*)alloc(256);
    f16* featsB = (f16*)alloc((size_t)(N + 1) * 128 * 2);
    f16* feats1h = (f16*)alloc((size_t)(N + 1) * 64 * 2);
    f16* xdown = (f16*)alloc((size_t)NSITES * 64 * 2);
    f16* x0 = (f16*)alloc((size_t)NSITES * 64 * 2);
    f16* y1 = (f16*)alloc((size_t)NSITES * 64 * 2);
    f16* y2 = (f16*)alloc((size_t)NSITES * 64 * 2);
    f16* thh = (f16*)alloc((size_t)NSITES * 32 * 2);
    f16* ph = (f16*)alloc((size_t)NSITES * 48 * 2);
    float* xF = (float*)alloc((size_t)NSITES * 64 * 4);
    f16* wc1 = (f16*)alloc((size_t)27 * 8192 * 2);
    f16* wdnh = (f16*)alloc((size_t)8 * 4096 * 2);
    f16* wc2h = (f16*)alloc((size_t)27 * 4096 * 2);
    f16* wfA = (f16*)alloc((size_t)L * 27 * 2048 * 2);
    f16* wfB = (f16*)alloc((size_t)L * 27 * 1536 * 2);
    f16* w12h = (f16*)alloc((size_t)L * 512 * 2);
    float* bA = (float*)alloc((size_t)L * 32 * 4);
    float* bB = (float*)alloc((size_t)L * 48 * 4);
    (void)ws_size;

    float* out = (float*)d_out;
    (void)out_size;
    (void)n_in;

    init_kernel<<<(GD * GD * GD + 255) / 256, 256, 0, stream>>>(idx_grid, ds_mask, zrow,
                                                                feats1h + (size_t)N * 64);
    {
        int mx = N > M ? N : M;
        scatter_kernel<<<(mx + 255) / 256, 256, 0, stream>>>(coords, N, coords_ds, M, idx_grid,
                                                             ds_mask);
    }
    {
        int tot = 27 * 8192 + 8 * 4096 + 27 * 4096 + L * 27 * 2048 + L * 27 * 1536 + L * 512 +
                  L * 32 + L * 48;
        pack_kernel<<<(tot + 255) / 256, 256, 0, stream>>>(
            w_fuse, w_down, w_conv2, w_p00, w_p01, w_p10, w_p11, w_p12, b_p00, b_p01, b_p10, b_p11,
            L, wc1, wdnh, wc2h, wfA, wfB, w12h, bA, bB);
    }
    fusef_kernel<<<((N + 1) * 128 + 255) / 256, 256, 0, stream>>>(fc1, fref, N, featsB);

    conv1_mfma<<<(N + 127) / 128, 512, 0, stream>>>(coords, N, featsB, wc1, b_fuse, idx_grid,
                                                    feats1h);
    down_mfma<<<NSITES / 128, 512, 0, stream>>>(feats1h, N, idx_grid, wdnh, b_down, ds_mask,
                                                xdown);
    dconv_kernel<64, 64, 2, 64>
        <<<256, 512, 0, stream>>>(xdown, wc2h, b_conv2, ds_mask, zrow, x0);

    f16* x = x0;
    for (int l = 0; l < L; ++l) {
        dconv_kernel<64, 32, 2, 0>
            <<<256, 512, 0, stream>>>(x, wfA + (size_t)l * 27 * 2048, bA + l * 32, ds_mask, zrow,
                                      thh);
        dconv_kernel<32, 48, 1, 32>
            <<<256, 512, 0, stream>>>(thh, wfB + (size_t)l * 27 * 1536, bB + l * 48, ds_mask, zrow,
                                      ph);
        if (l < L - 1) {
            f16* yn = (l == 0) ? y1 : y2;
            tail_kernel<f16><<<NSITES / 256, 256, 0, stream>>>(ph, x, w12h + (size_t)l * 512,
                                                               b_p12 + l * 32, ds_mask, yn);
            x = yn;
        } else {
            tail_kernel<float><<<NSITES / 256, 256, 0, stream>>>(ph, x, w12h + (size_t)l * 512,
                                                                 b_p12 + l * 32, ds_mask, xF);
        }
    }

    gather_kernel<<<(M * 64 + 255) / 256, 256, 0, stream>>>(xF, coords_ds, M, out);
}